// Round 8
// baseline (14885.420 us; speedup 1.0000x reference)
//
#include <hip/hip_runtime.h>

#define Bb  128
#define Tt  512
#define Ff  512
#define Hh  1024
#define BH  (Bb*Hh)
#define WGS 512
#define NBLK 256
#define NPH 515
#define PBH (Bb*4096)

#define OFF_H1   0u
#define OFF_H2   524288u
#define OFF_H2F  1048576u
#define OFF_BAR  1572864u
#define OFF_PB   1576960u
#define OFF_PBX  5771264u
#define OFF_XB   9965568u
#define WS_NEED  77074432u

typedef __attribute__((ext_vector_type(8))) short short8;
typedef __attribute__((ext_vector_type(4))) float f32x4;
typedef __attribute__((ext_vector_type(16))) float f32x16;

__device__ __forceinline__ short f2bf(float f){
  union { float fv; unsigned u; } v; v.fv = f;
  unsigned r = v.u + 0x7fffu + ((v.u >> 16) & 1u);   // RNE
  return (short)(r >> 16);
}
__device__ __forceinline__ float sigm(float x){ return 1.f/(1.f+__expf(-x)); }

__device__ __forceinline__ f32x16 mfma32(short8 a, short8 b, f32x16 c){
  return __builtin_amdgcn_mfma_f32_32x32x16_bf16(a, b, c, 0, 0, 0);
}

// coherent (LLC) ops: sc0 sc1 bypass stale L1/L2 copies
__device__ __forceinline__ short8 scld8(const short* p){
  short8 d;
  asm volatile("global_load_dwordx4 %0, %1, off sc0 sc1" : "=v"(d) : "v"(p) : "memory");
  return d;
}
__device__ __forceinline__ f32x4 scldf4(const float* p){
  f32x4 d;
  asm volatile("global_load_dwordx4 %0, %1, off sc0 sc1" : "=v"(d) : "v"(p) : "memory");
  return d;
}
__device__ __forceinline__ void sstf4(float* p, f32x4 v){
  asm volatile("global_store_dwordx4 %0, %1, off sc0 sc1" :: "v"(p), "v"(v) : "memory");
}
__device__ __forceinline__ void ssth(short* p, short v){
  asm volatile("global_store_short %0, %1, off sc0 sc1"
               :: "v"(p), "v"((unsigned)(unsigned short)v) : "memory");
}
__device__ __forceinline__ void drain_vm(){
  asm volatile("s_waitcnt vmcnt(0)" ::: "memory");
  __builtin_amdgcn_sched_barrier(0);
}

__global__ void __launch_bounds__(WGS) conv_x(const float* __restrict__ xf,
                                              short* __restrict__ xb){
  const size_t i = ((size_t)blockIdx.x * WGS + threadIdx.x) * 8;
  float4 u0 = *(const float4*)(xf + i);
  float4 u1 = *(const float4*)(xf + i + 4);
  short8 v;
  v[0]=f2bf(u0.x); v[1]=f2bf(u0.y); v[2]=f2bf(u0.z); v[3]=f2bf(u0.w);
  v[4]=f2bf(u1.x); v[5]=f2bf(u1.y); v[6]=f2bf(u1.z); v[7]=f2bf(u1.w);
  *(short8*)(xb + i) = v;
}

// Groups (bid>>6): 0=A layer1, 1=B PB=h1@Wih2, 2=C layer2, 3=X PBX=x@Wih1
// Per group 64 CUs: sub = rowhalf(1b) x colrange(5b). CU = 64 rows x 32 hcols.
// Phase p: X: gx[p] (p<512); A: step p-1 (1..512); B: step p-2 (2..513); C: step p-3 (3..514)
// R8: R5-proven sync discipline. ALL waves issue loads, drain ONCE (one
// exposed LLC roundtrip), write disjoint LDS halves, plain __syncthreads.
// No asm-load results live across any barrier.
__global__ void __launch_bounds__(WGS, 1) lstm4(
    const short* __restrict__ xb,
    const float* __restrict__ Wih1, const float* __restrict__ Whh1,
    const float* __restrict__ bih1, const float* __restrict__ bhh1,
    const float* __restrict__ Wih2, const float* __restrict__ Whh2,
    const float* __restrict__ bih2, const float* __restrict__ bhh2,
    short* __restrict__ h1, short* __restrict__ h2,
    float* __restrict__ PB, float* __restrict__ PBX,
    float* __restrict__ h2f32, unsigned* __restrict__ bar)
{
  extern __shared__ char lds[];
  // stage: ABC [kh(64K)][64 rows][1024B swizzled], X [kh(32K)][64 rows][512B]
  // F (aliases stage after compute-sync): [2 kh][64 rows][132] f32 = 67584 B
  float* F  = (float*)lds;
  float* Lb = (float*)(lds + 131072);   // 128 f32 bias sums

  const int bid = blockIdx.x, tid = threadIdx.x;
  const int grp = bid >> 6;
  const int sub = bid & 63;
  const int rbase = (sub >> 5) << 6;    // first batch row (0 or 64)
  const int c0  = (sub & 31) << 5;      // first owned h-col (32 per CU)
  const int lane = tid & 63, wv = tid >> 6;
  const int tc = lane & 31, hi = lane >> 5;
  const int kh = wv & 1, cth = wv >> 1; // wave = (col-tile cth<4, k-half kh)
  const int t256 = (cth << 6) + lane;   // index within kh-class [0,256)
  const int slot = bid & 7;

  if (tid < 128){
    const int hc = tid >> 2, g = tid & 3;
    float v = 0.f;
    if (grp == 0) v = bih1[(g<<10)+c0+hc] + bhh1[(g<<10)+c0+hc];
    if (grp == 2) v = bih2[(g<<10)+c0+hc] + bhh2[(g<<10)+c0+hc];
    Lb[tid] = v;
  }

  // ---- weights into registers, B-frag layout, once ----
  const float* Wsrc = (grp==0)?Whh1:(grp==1)?Wih2:(grp==2)?Whh2:Wih1;
  const int wrow = (tc&3)*Hh + c0 + (cth<<3) + (tc>>2);  // gate-interleaved col
  short8 bfr[32];
  if (grp != 3){
    const float* wb = Wsrc + (size_t)wrow*Hh + (kh<<9) + (hi<<3);
    #pragma unroll
    for (int f = 0; f < 32; ++f){
      float4 u0 = *(const float4*)(wb + (f<<4));
      float4 u1 = *(const float4*)(wb + (f<<4) + 4);
      short8 v;
      v[0]=f2bf(u0.x); v[1]=f2bf(u0.y); v[2]=f2bf(u0.z); v[3]=f2bf(u0.w);
      v[4]=f2bf(u1.x); v[5]=f2bf(u1.y); v[6]=f2bf(u1.z); v[7]=f2bf(u1.w);
      bfr[f] = v;
    }
  } else {
    const float* wb = Wsrc + (size_t)wrow*Ff + (kh<<8) + (hi<<3);
    #pragma unroll
    for (int f = 0; f < 16; ++f){
      float4 u0 = *(const float4*)(wb + (f<<4));
      float4 u1 = *(const float4*)(wb + (f<<4) + 4);
      short8 v;
      v[0]=f2bf(u0.x); v[1]=f2bf(u0.y); v[2]=f2bf(u0.z); v[3]=f2bf(u0.w);
      v[4]=f2bf(u1.x); v[5]=f2bf(u1.y); v[6]=f2bf(u1.z); v[7]=f2bf(u1.w);
      bfr[f] = v;
    }
  }
  __syncthreads();

  float cst[4] = {0.f,0.f,0.f,0.f};

  for (int p = 0; p < NPH; ++p){
    const bool act = (grp==0) ? (p>=1 && p<=512)
                   : (grp==1) ? (p>=2 && p<=513)
                   : (grp==2) ? (p>=3 && p<=514)
                   :            (p < 512);
    const short* sh = ((grp==2) ? h2 : h1) + (p&1)*BH;

    f32x4 pre[4] = {{0,0,0,0},{0,0,0,0},{0,0,0,0},{0,0,0,0}};

    // ---- issue ALL loads, drain once, write LDS (no loads cross barriers) ----
    if (act){
      short8 t[16];
      if (grp == 0 || grp == 2){
        const float* src = ((grp==0)?PBX:PB) + (size_t)((p+1)&1)*PBH;
        #pragma unroll
        for (int s4 = 0; s4 < 4; ++s4){
          const int id = (s4<<9)+tid;
          pre[s4] = scldf4(src + (size_t)(rbase + (id>>5))*4096 + ((c0 + (id&31))<<2));
        }
      }
      if (grp != 3){
        #pragma unroll
        for (int i = 0; i < 16; ++i){
          const int u = (i<<8)+t256;
          t[i] = scld8(sh + (size_t)(rbase + (u>>6))*Hh + (kh<<9) + ((u&63)<<3));
        }
        drain_vm();
        #pragma unroll
        for (int i = 0; i < 16; ++i){
          const int u = (i<<8)+t256, row = u>>6;
          *(short8*)(lds + (kh<<16) + (row<<10) + ((((u&63)<<4)) ^ (row<<4))) = t[i];
        }
      } else {
        #pragma unroll
        for (int i = 0; i < 8; ++i){
          const int u = (i<<8)+t256;
          t[i] = *(const short8*)(xb + ((size_t)(rbase + (u>>5))*Tt + p)*Ff + (kh<<8) + ((u&31)<<3));
        }
        drain_vm();
        #pragma unroll
        for (int i = 0; i < 8; ++i){
          const int u = (i<<8)+t256, row = u>>5;
          *(short8*)(lds + (kh<<15) + (row<<9) + ((((u&31)<<4)) ^ ((row&31)<<4))) = t[i];
        }
      }
    }
    __syncthreads();                    // stage complete (both kh halves)

    f32x16 a0, a1;
    #pragma unroll
    for (int i = 0; i < 16; ++i){ a0[i]=0.f; a1[i]=0.f; }

    // ---- compute: each wave reads only its own kh buffer ----
    if (act){
      if (grp != 3){
        const int r0 = tc, r1 = 32+tc;
        const char* base = lds + (kh<<16);
        #pragma unroll
        for (int ci = 0; ci < 32; ++ci){
          const int ko = (ci<<5) | (hi<<4);
          a0 = mfma32(*(const short8*)(base + (r0<<10) + (ko ^ (r0<<4))), bfr[ci], a0);
          a1 = mfma32(*(const short8*)(base + (r1<<10) + (ko ^ (r1<<4))), bfr[ci], a1);
        }
      } else {
        const int r0 = tc, r1 = 32+tc;
        const char* base = lds + (kh<<15);
        #pragma unroll
        for (int ci = 0; ci < 16; ++ci){
          const int ko = (ci<<5) | (hi<<4);
          a0 = mfma32(*(const short8*)(base + (r0<<9) + (ko ^ ((r0&31)<<4))), bfr[ci], a0);
          a1 = mfma32(*(const short8*)(base + (r1<<9) + (ko ^ ((r1&31)<<4))), bfr[ci], a1);
        }
      }
    }
    __syncthreads();                    // all LDS reads done; F may alias

    // ---- dump partials: F[kh][64 rows][132] (gate-interleaved cols) ----
    if (act){
      const int colf = (cth<<5) + tc;
      #pragma unroll
      for (int rg = 0; rg < 16; ++rg){
        const int rl = (rg&3) + ((rg>>2)<<3) + (hi<<2);
        F[((kh<<6) + rl)*132 + colf]      = a0[rg];
        F[((kh<<6) + 32 + rl)*132 + colf] = a1[rg];
      }
    }
    __syncthreads();                    // F complete

    // ---- update / exchange ----
    if (act){
      #pragma unroll
      for (int s = 0; s < 4; ++s){
        const int id = (s<<9)+tid, row = id>>5, hc = id&31;
        f32x4 q = *(f32x4*)&F[row*132 + (hc<<2)];
        q += *(f32x4*)&F[(64+row)*132 + (hc<<2)];
        const int grow = rbase + row, gcol = c0 + hc;
        if (grp == 0 || grp == 2){
          f32x4 bb = *(f32x4*)&Lb[hc<<2];
          float gi=q[0]+pre[s][0]+bb[0], gf=q[1]+pre[s][1]+bb[1];
          float gg=q[2]+pre[s][2]+bb[2], go=q[3]+pre[s][3]+bb[3];
          float iv=sigm(gi), fv=sigm(gf), gv=tanhf(gg), ov=sigm(go);
          cst[s] = fv*cst[s] + iv*gv;
          float hv = ov*tanhf(cst[s]);
          if (grp == 0){
            ssth(h1 + ((p+1)&1)*BH + (size_t)grow*Hh + gcol, f2bf(hv));
          } else {
            ssth(h2 + ((p+1)&1)*BH + (size_t)grow*Hh + gcol, f2bf(hv));
            if (p == 514) h2f32[(size_t)grow*Hh + gcol] = hv;
          }
        } else if (grp == 1){
          sstf4(PB + (size_t)(p&1)*PBH + (size_t)grow*4096 + (gcol<<2), q);
        } else {
          sstf4(PBX + (size_t)(p&1)*PBH + (size_t)grow*4096 + (gcol<<2), q);
        }
      }
    }

    // ---- two-level relaxed grid barrier (syncthreads drains sc-stores) ----
    __syncthreads();
    if (tid == 0){
      unsigned prev = __hip_atomic_fetch_add(bar + (slot<<6), 1u,
                        __ATOMIC_RELAXED, __HIP_MEMORY_SCOPE_AGENT);
      if (prev == 32u*(p+1) - 1u)
        __hip_atomic_fetch_add(bar + 768, 1u,
                        __ATOMIC_RELAXED, __HIP_MEMORY_SCOPE_AGENT);
      while (__hip_atomic_load(bar + 768,
                        __ATOMIC_RELAXED, __HIP_MEMORY_SCOPE_AGENT) < 8u*(p+1))
        __builtin_amdgcn_s_sleep(1);
    }
    __syncthreads();
  }
}

__global__ void final_linear(const float* __restrict__ h2, const float* __restrict__ Wl,
                             const float* __restrict__ bl, float* __restrict__ out){
  __shared__ float red[256];
  const int b = blockIdx.x, t = threadIdx.x;
  float s = 0.f;
  for (int k = t; k < Hh; k += 256) s += h2[(size_t)b*Hh + k] * Wl[k];
  red[t] = s; __syncthreads();
  for (int off = 128; off > 0; off >>= 1){ if (t < off) red[t] += red[t+off]; __syncthreads(); }
  if (t == 0) out[b] = red[0] + bl[0];
}

extern "C" void kernel_launch(void* const* d_in, const int* in_sizes, int n_in,
                              void* d_out, int out_size, void* d_ws, size_t ws_size,
                              hipStream_t stream) {
  (void)in_sizes; (void)n_in; (void)out_size;
  const float* x    = (const float*)d_in[0];
  const float* Wih1 = (const float*)d_in[1];
  const float* Whh1 = (const float*)d_in[2];
  const float* bih1 = (const float*)d_in[3];
  const float* bhh1 = (const float*)d_in[4];
  const float* Wih2 = (const float*)d_in[5];
  const float* Whh2 = (const float*)d_in[6];
  const float* bih2 = (const float*)d_in[7];
  const float* bhh2 = (const float*)d_in[8];
  const float* Wlin = (const float*)d_in[9];
  const float* blin = (const float*)d_in[10];
  float* out = (float*)d_out;

  if (ws_size < WS_NEED) return;
  char* ws = (char*)d_ws;
  short*    h1b   = (short*)(ws + OFF_H1);
  short*    h2b   = (short*)(ws + OFF_H2);
  float*    h2f32 = (float*)(ws + OFF_H2F);
  unsigned* bar   = (unsigned*)(ws + OFF_BAR);
  float*    PB    = (float*)(ws + OFF_PB);
  float*    PBX   = (float*)(ws + OFF_PBX);
  short*    xb    = (short*)(ws + OFF_XB);

  hipMemsetAsync(d_ws, 0, OFF_PB, stream);   // h-state, h2f32, barrier
  conv_x<<<dim3(8192), dim3(WGS), 0, stream>>>(x, xb);
  hipFuncSetAttribute(reinterpret_cast<const void*>(lstm4),
                      hipFuncAttributeMaxDynamicSharedMemorySize, 131584);
  lstm4<<<dim3(NBLK), dim3(WGS), 131584, stream>>>(
      xb, Wih1, Whh1, bih1, bhh1, Wih2, Whh2, bih2, bhh2,
      h1b, h2b, PB, PBX, h2f32, bar);
  final_linear<<<dim3(Bb), dim3(256), 0, stream>>>(h2f32, Wlin, blin, out);
}